// Round 12
// baseline (225.381 us; speedup 1.0000x reference)
//
#include <hip/hip_runtime.h>
#include <math.h>

// Problem constants
constexpr int Bn = 8, Cn = 128, Ln = 4096;

// Workspace layout (float offsets). o1/o3, z, s, xbca, Sprev, T, s2, xX bf16.
constexpr size_t OFF_O1   = 0;          // bf16 o1; later bf16 o3 (aliased)
constexpr size_t OFF_O2   = 4194304;    // (dead — dw+fcin fused)
constexpr size_t OFF_S    = 8388608;    // bf16: 8*4096*32 ushort
constexpr size_t OFF_Z    = 9437184;    // bf16 zT[dir][p=64][b=8][l=4096]
constexpr size_t OFF_WT   = 11534336;   // bf16 WT[dir][n=272][k=32]
constexpr size_t OFF_XBCA = 13631488;   // bf16: 2 dirs x 6,291,456 ushort (cols 64..191 used)
constexpr size_t OFF_DTS  = 26214400;
constexpr size_t OFF_CUM  = 26279936;
constexpr size_t OFF_T    = 26345472;   // bf16 2 dirs x 2,097,152; reused for BN partials
constexpr size_t OFF_SPREV= 30539776;   // bf16: 2 dirs x 2,097,152 ushort
constexpr size_t OFF_S2A  = 34734080;   // bf16
constexpr size_t OFF_S2B  = 35782656;   // bf16
constexpr size_t OFF_BN   = 36831232;
constexpr size_t OFF_XX   = 36831488;   // bf16 xX[dir][chunk=512][c=64][t=64]
constexpr size_t OFF_WB1  = 38928640;   // bf16 lin1_w  [k=128][c=128]
constexpr size_t OFF_WB4  = 38936832;   // bf16 conv4_w [k=128][c=128]
constexpr size_t OFF_WN   = 38945024;   // bf16 wn[dir][d=32][p=64]
constexpr size_t OFF_O3   = 0;

constexpr long XSTRIDE_H = 6291456;   // ushort elements per dir
constexpr long TSTRIDE = 2097152;     // element stride per dir (u16 for T and Sprev)

typedef __attribute__((ext_vector_type(8))) short short8;
typedef __attribute__((ext_vector_type(4))) float f32x4;
typedef __attribute__((ext_vector_type(4))) unsigned short us4;
typedef __attribute__((ext_vector_type(8))) unsigned short us8;

__device__ __forceinline__ float siluf(float v) { return v / (1.0f + expf(-v)); }

__device__ __forceinline__ unsigned short tobf(float f) {
  unsigned int u = __float_as_uint(f);
  u += 0x7FFFu + ((u >> 16) & 1u);     // RNE
  return (unsigned short)(u >> 16);
}

__device__ __forceinline__ float frombf(unsigned short u) {
  return __uint_as_float(((unsigned int)u) << 16);
}

__device__ __forceinline__ unsigned int pk2(float a, float b) {
  return (unsigned int)tobf(a) | ((unsigned int)tobf(b) << 16);
}

// 8 consecutive bf16 from LDS via 4 dword reads (>=4B-aligned offsets)
__device__ __forceinline__ short8 ldfrag(const unsigned short* p) {
  union { unsigned int u[4]; short8 s; } cv;
  cv.u[0] = *(const unsigned int*)(p);
  cv.u[1] = *(const unsigned int*)(p + 2);
  cv.u[2] = *(const unsigned int*)(p + 4);
  cv.u[3] = *(const unsigned int*)(p + 6);
  return cv.s;
}

// K0: one-time weight prep: lin1_w/conv4_w -> bf16; wn = normw*Wout bf16;
//     WT[dir][n(272)][k(32)] transpose of Win (blocks 4,5).
__global__ void k_prepc(const float* __restrict__ lin1_w, const float* __restrict__ conv4_w,
                        const float* __restrict__ normw, const float* __restrict__ Wout,
                        const float* __restrict__ Win,
                        unsigned short* __restrict__ wb1, unsigned short* __restrict__ wb4,
                        unsigned short* __restrict__ wn, unsigned short* __restrict__ WT) {
  int blk = blockIdx.x, tid = threadIdx.x;
  if (blk < 2) {
    const float* src = blk ? conv4_w : lin1_w;
    unsigned short* dst = blk ? wb4 : wb1;
    for (int idx = tid * 4; idx < 16384; idx += 1024) {
      float4 v = *(const float4*)&src[idx];
      us4 o;
      o[0] = tobf(v.x); o[1] = tobf(v.y); o[2] = tobf(v.z); o[3] = tobf(v.w);
      *(us4*)&dst[idx] = o;
    }
  } else if (blk < 4) {
    int dir = blk - 2;
    for (int idx = tid; idx < 2048; idx += 256) {
      int d = idx >> 6, p = idx & 63;
      wn[dir * 2048 + idx] = tobf(normw[dir * 64 + p] * Wout[(long)dir * 2048 + p * 32 + d]);
    }
  } else {
    int dir = blk - 4;
    for (int idx = tid; idx < 272 * 32; idx += 256) {
      int n = idx >> 5, kk = idx & 31;
      float v = (n < 257) ? Win[dir * 32 * 257 + kk * 257 + n] : 0.f;
      WT[dir * 8704 + idx] = tobf(v);
    }
  }
}

// K1: o1[b,c,l] = sum_k x[b,k,l]*w[k,c] + bias[c] — MFMA bf16, K=128. bf16 out.
__global__ __launch_bounds__(256) void k_lin1(const float* __restrict__ x,
                                              const unsigned short* __restrict__ wb,
                                              const float* __restrict__ bias,
                                              unsigned short* __restrict__ o1) {
  __shared__ unsigned short wT[64][140];
  __shared__ unsigned short xT[64][140];
  int b = blockIdx.y, l0 = blockIdx.x * 64, cb = blockIdx.z * 64;
  int tid = threadIdx.x, lane = tid & 63, mt = tid >> 6;
  int q = lane >> 4, i = lane & 15;
  int c4 = (tid & 15) * 4, k0 = (tid >> 4) * 2;
#pragma unroll
  for (int s = 0; s < 4; ++s) {
    int k = k0 + s * 32;
    us4 w0 = *(const us4*)&wb[k * 128 + cb + c4];
    us4 w1 = *(const us4*)&wb[(k + 1) * 128 + cb + c4];
#pragma unroll
    for (int j = 0; j < 4; ++j)
      *(unsigned int*)&wT[c4 + j][k] =
          (unsigned int)w0[j] | ((unsigned int)w1[j] << 16);
    float4 x0 = *(const float4*)&x[((long)b * 128 + k) * 4096 + l0 + c4];
    float4 x1 = *(const float4*)&x[((long)b * 128 + k + 1) * 4096 + l0 + c4];
    *(unsigned int*)&xT[c4 + 0][k] = pk2(x0.x, x1.x);
    *(unsigned int*)&xT[c4 + 1][k] = pk2(x0.y, x1.y);
    *(unsigned int*)&xT[c4 + 2][k] = pk2(x0.z, x1.z);
    *(unsigned int*)&xT[c4 + 3][k] = pk2(x0.w, x1.w);
  }
  __syncthreads();
  short8 af[4];
#pragma unroll
  for (int kk = 0; kk < 4; ++kk)
    af[kk] = ldfrag(&wT[mt * 16 + i][q * 8 + 32 * kk]);
  float bv[4];
#pragma unroll
  for (int r2 = 0; r2 < 4; ++r2) bv[r2] = bias[cb + 16 * mt + q * 4 + r2];
#pragma unroll
  for (int nt = 0; nt < 4; ++nt) {
    f32x4 d = {0.f, 0.f, 0.f, 0.f};
#pragma unroll
    for (int kk = 0; kk < 4; ++kk) {
      short8 bfr = ldfrag(&xT[nt * 16 + i][q * 8 + 32 * kk]);
      d = __builtin_amdgcn_mfma_f32_16x16x32_bf16(af[kk], bfr, d, 0, 0, 0);
    }
#pragma unroll
    for (int r2 = 0; r2 < 4; ++r2) {
      int c = 16 * mt + q * 4 + r2;
      o1[((long)b * 128 + cb + c) * 4096 + l0 + nt * 16 + i] = tobf(d[r2] + bv[r2]);
    }
  }
}

// K2+K3 fused: depthwise 3x3 + bias + silu + fc_in projection. Block = (h-row, b),
// all 128 channels. o2 intermediate eliminated. LDS 64KB (2 blocks/CU).
// Conv thread map (c0=(tid>>5)*16, w0=(tid&31)*2): lanes span 32 banks (no conflict).
__global__ __launch_bounds__(256) void k_dwfc(
    const unsigned short* __restrict__ o1, const float* __restrict__ wgt,
    const float* __restrict__ bias, const float* __restrict__ fcw,
    unsigned short* __restrict__ sb) {
  __shared__ unsigned short pin[3][128][64];   // rows h-1,h,h+1 x c x w (48KB)
  __shared__ float fw[128][32];                // fc_in weights f32 (16KB)
  int h = blockIdx.x, b = blockIdx.y, tid = threadIdx.x;

  // ---- stage input rows (zeros outside) + fc weights ----
  for (int u = tid; u < 3072; u += 256) {
    int off = u * 8;
    int hr = off >> 13, rem = off & 8191;
    int c = rem >> 6, w = rem & 63;
    int hh = h - 1 + hr;
    us8 v;
    if (hh >= 0 && hh < 64) {
      v = *(const us8*)&o1[((long)b * 128 + c) * 4096 + hh * 64 + w];
    } else {
#pragma unroll
      for (int j = 0; j < 8; ++j) v[j] = 0;
    }
    *(us8*)&pin[hr][c][w] = v;
  }
  for (int u = tid * 4; u < 4096; u += 1024) {
    int c = u >> 5, d = u & 31;
    *(float4*)&fw[c][d] = *(const float4*)&fcw[c * 32 + d];
  }
  __syncthreads();

  // ---- depthwise conv + silu: 16 c x 2 w per thread ----
  int w0 = (tid & 31) * 2, c0 = (tid >> 5) * 16;
  float ocv[16][2];
#pragma unroll
  for (int ci = 0; ci < 16; ++ci) {
    int c = c0 + ci;
    float wr[9];
#pragma unroll
    for (int j = 0; j < 9; ++j) wr[j] = wgt[c * 9 + j];
    float bv = bias[c];
    float rv[3][4];
#pragma unroll
    for (int dh = 0; dh < 3; ++dh)
#pragma unroll
      for (int j = 0; j < 4; ++j) {
        int ww = w0 - 1 + j;
        rv[dh][j] = (ww >= 0 && ww < 64) ? frombf(pin[dh][c][ww]) : 0.f;
      }
#pragma unroll
    for (int wi = 0; wi < 2; ++wi) {
      float acc = bv;
#pragma unroll
      for (int dh = 0; dh < 3; ++dh)
#pragma unroll
        for (int dw = 0; dw < 3; ++dw)
          acc += rv[dh][wi + dw] * wr[dh * 3 + dw];
      ocv[ci][wi] = siluf(acc);
    }
  }
  __syncthreads();
  // write conv result (bf16, == old o2 bits) into plane 0
#pragma unroll
  for (int ci = 0; ci < 16; ++ci)
    *(unsigned int*)&pin[0][c0 + ci][w0] = pk2(ocv[ci][0], ocv[ci][1]);
  __syncthreads();

  // ---- fc_in: s[l][d] = sum_c dwout[c][w] * fw[c][d]; thread = (w, 8-d group) ----
  int w = tid & 63, d0 = (tid >> 6) * 8;
  float acc[8] = {};
  for (int c = 0; c < 128; ++c) {
    float a = frombf(pin[0][c][w]);
    float4 f0 = *(const float4*)&fw[c][d0];
    float4 f1 = *(const float4*)&fw[c][d0 + 4];
    acc[0] += a * f0.x; acc[1] += a * f0.y;
    acc[2] += a * f0.z; acc[3] += a * f0.w;
    acc[4] += a * f1.x; acc[5] += a * f1.y;
    acc[6] += a * f1.z; acc[7] += a * f1.w;
  }
  long ob = ((long)b * 4096 + h * 64 + w) * 32 + d0;
#pragma unroll
  for (int j = 0; j < 4; ++j)
    *(unsigned int*)&sb[ob + 2 * j] = pk2(acc[2 * j], acc[2 * j + 1]);
}

// K4: in_proj (MFMA bf16, K=32) + causal conv1d + silu + dt softplus + cum
//     + fused chunk summary T[p][n] (MFMA bf16, T stored bf16).
__global__ __launch_bounds__(256) void k_inprojconv(
    const unsigned short* __restrict__ sb, const unsigned short* __restrict__ WT,
    const float* __restrict__ conv_w, const float* __restrict__ conv_b,
    const float* __restrict__ dt_bias, const float* __restrict__ A_log,
    unsigned short* __restrict__ zT, unsigned short* __restrict__ xbca,
    unsigned short* __restrict__ xX,
    float* __restrict__ dts, float* __restrict__ cum,
    unsigned short* __restrict__ Tg) {
  __shared__ unsigned short xbcT[192][82];   // [channel][t], pitch 82: conflict-free
  __shared__ float dtL[64];                  // raw dt MFMA outputs
  __shared__ float dtsS[64], cumSS[64], fL[64];
  int dir = blockIdx.z, b = blockIdx.y, l0 = blockIdx.x * 64;
  int tid = threadIdx.x, lane = tid & 63, mt = tid >> 6;
  int q = lane >> 4, i = lane & 15;
  long rowbase = (long)b * 4096 + l0;
  const unsigned short* W = WT + (long)dir * 8704;
  const short8 zfrag = {0, 0, 0, 0, 0, 0, 0, 0};

  if (mt == 0) {
    // ---- z columns (n 0..63) + dt column, l0-aligned rows ----
    short8 afr[4];
#pragma unroll
    for (int rt = 0; rt < 4; ++rt) {
      int l = l0 + 16 * rt + i;
      int lsrc = dir ? (4095 - l) : l;
      afr[rt] = *(const short8*)&sb[((long)b * 4096 + lsrc) * 32 + q * 8];
    }
#pragma unroll
    for (int ct = 0; ct < 4; ++ct) {
      int n = 16 * ct + i;
      short8 bfr = *(const short8*)&W[n * 32 + q * 8];
      unsigned short* zrow = zT + (((long)dir * 64 + n) * 8 + b) * 4096 + l0 + q * 4;
#pragma unroll
      for (int rt = 0; rt < 4; ++rt) {
        f32x4 d = {0.f, 0.f, 0.f, 0.f};
        d = __builtin_amdgcn_mfma_f32_16x16x32_bf16(afr[rt], bfr, d, 0, 0, 0);
        us4 pk;
        pk[0] = tobf(d[0]); pk[1] = tobf(d[1]);
        pk[2] = tobf(d[2]); pk[3] = tobf(d[3]);
        *(us4*)&zrow[16 * rt] = pk;
      }
    }
    {
      short8 bfr = *(const short8*)&W[(256 + i) * 32 + q * 8];
#pragma unroll
      for (int rt = 0; rt < 4; ++rt) {
        f32x4 d = {0.f, 0.f, 0.f, 0.f};
        d = __builtin_amdgcn_mfma_f32_16x16x32_bf16(afr[rt], bfr, d, 0, 0, 0);
        if (i == 0) {
#pragma unroll
          for (int r2 = 0; r2 < 4; ++r2) dtL[16 * rt + q * 4 + r2] = d[r2];
        }
      }
    }
  } else {
    // ---- xbc columns (n 64..255), rows with -3 conv halo ----
    short8 afr[5];
#pragma unroll
    for (int rt = 0; rt < 5; ++rt) {
      int l = l0 - 3 + 16 * rt + i;
      if (l >= 0 && l < 4096) {
        int lsrc = dir ? (4095 - l) : l;
        afr[rt] = *(const short8*)&sb[((long)b * 4096 + lsrc) * 32 + q * 8];
      } else {
        afr[rt] = zfrag;
      }
    }
#pragma unroll
    for (int cti = 0; cti < 4; ++cti) {
      int n = 16 * (mt * 4 + cti) + i;
      short8 bfr = *(const short8*)&W[n * 32 + q * 8];
      int cc = n - 64;
#pragma unroll
      for (int rt = 0; rt < 5; ++rt) {
        f32x4 d = {0.f, 0.f, 0.f, 0.f};
        d = __builtin_amdgcn_mfma_f32_16x16x32_bf16(afr[rt], bfr, d, 0, 0, 0);
        int rr0 = 16 * rt + q * 4;
        unsigned int p0 = (unsigned int)tobf(d[0]) | ((unsigned int)tobf(d[1]) << 16);
        unsigned int p1 = (unsigned int)tobf(d[2]) | ((unsigned int)tobf(d[3]) << 16);
        *(unsigned int*)&xbcT[cc][rr0] = p0;
        *(unsigned int*)&xbcT[cc][rr0 + 2] = p1;
      }
    }
  }
  __syncthreads();

  if (tid < 192) {
    int c = tid;
    float cw0 = conv_w[dir * 768 + c * 4 + 0];
    float cw1 = conv_w[dir * 768 + c * 4 + 1];
    float cw2 = conv_w[dir * 768 + c * 4 + 2];
    float cw3 = conv_w[dir * 768 + c * 4 + 3];
    float cb2 = conv_b[dir * 192 + c];
    unsigned short* xp = xbca + (long)dir * XSTRIDE_H;
    float win0 = 0.f, win1 = 0.f, win2 = 0.f, win3 = 0.f;
    for (int rp = 0; rp < 34; ++rp) {
      unsigned int pk = *(const unsigned int*)&xbcT[c][rp * 2];
      float a0 = frombf((unsigned short)(pk & 0xFFFFu));
      float a1 = frombf((unsigned short)(pk >> 16));
      int rr = rp * 2;
      win0 = win1; win1 = win2; win2 = win3; win3 = a0;
      if (rr >= 3 && rr <= 66) {
        float acc = cb2 + win0 * cw0 + win1 * cw1 + win2 * cw2 + win3 * cw3;
        float sv = siluf(acc);
        int t = rr - 3;
        if (c >= 64) xp[(rowbase + t) * 192 + c] = tobf(sv);  // B,C only
        if (c < 128) xbcT[c][t] = tobf(sv);   // X and B rows, trailing in-place write
      }
      win0 = win1; win1 = win2; win2 = win3; win3 = a1;
      if (rr + 1 >= 3 && rr + 1 <= 66) {
        float acc = cb2 + win0 * cw0 + win1 * cw1 + win2 * cw2 + win3 * cw3;
        float sv = siluf(acc);
        int t = rr - 2;
        if (c >= 64) xp[(rowbase + t) * 192 + c] = tobf(sv);
        if (c < 128) xbcT[c][t] = tobf(sv);
      }
    }
  } else {
    int ln = tid - 192;
    float v = dtL[ln] + dt_bias[dir];
    float sp = (v > 20.f) ? v : log1pf(expf(v));
    dts[dir * 32768 + rowbase + ln] = sp;
    dtsS[ln] = sp;
    float cd = -expf(A_log[dir]) * sp;
#pragma unroll
    for (int off = 1; off < 64; off <<= 1) {
      float u = __shfl_up(cd, off);
      if (ln >= off) cd += u;
    }
    cum[dir * 32768 + rowbase + ln] = cd;
    cumSS[ln] = cd;
  }
  __syncthreads();

  // bulk-copy raw X (LDS rows 0..63, t 0..63) -> xX[dir][chunk][c][t] (coalesced)
  {
    int r = tid >> 2, seg = (tid & 3) * 16;
    unsigned short* dst =
        xX + (((long)dir * 512 + b * 64 + blockIdx.x) * 64 + r) * 64 + seg;
#pragma unroll
    for (int j = 0; j < 8; ++j) {
      unsigned int v = *(const unsigned int*)&xbcT[r][seg + 2 * j];
      *(unsigned int*)(dst + 2 * j) = v;
    }
  }
  if (tid < 64) fL[tid] = expf(cumSS[63] - cumSS[tid]) * dtsS[tid];
  __syncthreads();

  // scale phase: xbcT rows 0..63 <- tobf(frombf(xbcT) * fL), in-place u32 RMW
  {
    int c = tid & 63, tb2 = (tid >> 6) * 16;
#pragma unroll
    for (int j = 0; j < 8; ++j) {
      int t = tb2 + 2 * j;
      unsigned int pk = *(const unsigned int*)&xbcT[c][t];
      float v0 = frombf((unsigned short)(pk & 0xFFFFu));
      float v1 = frombf((unsigned short)(pk >> 16));
      unsigned int po = (unsigned int)tobf(v0 * fL[t]) |
                        ((unsigned int)tobf(v1 * fL[t + 1]) << 16);
      *(unsigned int*)&xbcT[c][t] = po;
    }
  }
  __syncthreads();

  // MFMA-T: T[p][n] = sum_t fX[p][t] * B[n][t], K=64 (two K=32 MFMAs), bf16 out
  {
    short8 a0 = ldfrag(&xbcT[mt * 16 + i][q * 8]);
    short8 a1 = ldfrag(&xbcT[mt * 16 + i][q * 8 + 32]);
    unsigned short* Tp = Tg + (long)dir * TSTRIDE + ((long)(b * 64 + blockIdx.x)) * 4096;
#pragma unroll
    for (int nt = 0; nt < 4; ++nt) {
      short8 b0 = ldfrag(&xbcT[64 + nt * 16 + i][q * 8]);
      short8 b1 = ldfrag(&xbcT[64 + nt * 16 + i][q * 8 + 32]);
      f32x4 d = {0.f, 0.f, 0.f, 0.f};
      d = __builtin_amdgcn_mfma_f32_16x16x32_bf16(a0, b0, d, 0, 0, 0);
      d = __builtin_amdgcn_mfma_f32_16x16x32_bf16(a1, b1, d, 0, 0, 0);
#pragma unroll
      for (int r2 = 0; r2 < 4; ++r2)
        Tp[(mt * 16 + q * 4 + r2) * 64 + nt * 16 + i] = tobf(d[r2]);
    }
  }
}

// K7: inter-chunk state scan — 256 blocks (full CU coverage), bf16 T in, bf16 out.
__global__ void k_scan(const unsigned short* __restrict__ T, const float* __restrict__ cum,
                       unsigned short* __restrict__ Sprev) {
  __shared__ float E[64];
  int blk = blockIdx.x;            // 256 blocks
  int dirb = blk >> 4;             // dir*8 + b
  int dir = dirb >> 3, b = dirb & 7;
  int pn = (blk & 15) * 256 + threadIdx.x;
  const float* cp = cum + dir * 32768 + b * 4096;
  if (threadIdx.x < 64) E[threadIdx.x] = expf(cp[threadIdx.x * 64 + 63]);
  __syncthreads();
  const unsigned short* Tp = T + (long)dir * TSTRIDE + (long)b * 262144 + pn;
  unsigned short* Sp = Sprev + (long)dir * TSTRIDE + (long)b * 262144 + pn;
  float s0 = 0.f;
  float tb[16];
#pragma unroll
  for (int j = 0; j < 16; ++j) tb[j] = frombf(Tp[(long)j * 4096]);
  for (int kc = 0; kc < 4; ++kc) {
    float tn[16];
    if (kc < 3) {
#pragma unroll
      for (int j = 0; j < 16; ++j)
        tn[j] = frombf(Tp[(long)(kc * 16 + 16 + j) * 4096]);
    }
#pragma unroll
    for (int j = 0; j < 16; ++j) {
      int k = kc * 16 + j;
      Sp[(long)k * 4096] = tobf(s0);
      s0 = fmaf(E[k], s0, tb[j]);
    }
    if (kc < 3) {
#pragma unroll
      for (int j = 0; j < 16; ++j) tb[j] = tn[j];
    }
  }
}

// K8: per-chunk Y + gate + RMSNorm + out-proj — MFMA bf16.
// C / Sprev / B*dt / X / Wn fragments ALL direct from global (16B-contiguous);
// only Gb in LDS (~9 KB). One barrier (for cumS/dtS only).
__global__ __launch_bounds__(256) void k_chunkYout(
    const unsigned short* __restrict__ xbca, const float* __restrict__ dts,
    const float* __restrict__ cum, const unsigned short* __restrict__ Sprev,
    const float* __restrict__ Dp, const unsigned short* __restrict__ zT,
    const unsigned short* __restrict__ xX, const unsigned short* __restrict__ wn,
    unsigned short* __restrict__ s2a, unsigned short* __restrict__ s2b) {
  __shared__ unsigned short Gb[64][72];   // gated G, then ynorm
  __shared__ float cumS[64], dtS[64];
  int dir = blockIdx.y;
  int bk = blockIdx.x, b = bk >> 6, k = bk & 63;
  int tid = threadIdx.x, lane = tid & 63, mt = tid >> 6;
  int q = lane >> 4, i = lane & 15;
  const unsigned short* xp = xbca + (long)dir * XSTRIDE_H;
  const float* dtp = dts + dir * 32768;
  const float* cp = cum + dir * 32768;
  const unsigned short* Sp = Sprev + (long)dir * TSTRIDE;
  const unsigned short* xXp = xX + ((long)dir * 512 + bk) * 4096;  // [c=64][t=64]
  const unsigned short* wnp = wn + dir * 2048;                     // [d=32][p=64]
  long base = (long)b * 4096 + (long)k * 64;

  if (tid < 64) { cumS[tid] = cp[base + tid]; dtS[tid] = dtp[base + tid]; }
  __syncthreads();

  // C fragments direct from global (row base+mt*16+i, cols 128+q*8 / 160+q*8)
  const unsigned short* crow = &xp[(base + mt * 16 + i) * 192];
  short8 a0 = *(const short8*)&crow[128 + q * 8];
  short8 a1 = *(const short8*)&crow[160 + q * 8];

  // inter-chunk contribution: dint = C · Sprev (B-frags direct from global)
  f32x4 dint[4];
#pragma unroll
  for (int lt = 0; lt < 4; ++lt) {
    const unsigned short* sp8 = &Sp[(long)bk * 4096 + (lt * 16 + i) * 64 + q * 8];
    short8 b0 = *(const short8*)sp8;
    short8 b1 = *(const short8*)(sp8 + 32);
    f32x4 d = {0.f, 0.f, 0.f, 0.f};
    d = __builtin_amdgcn_mfma_f32_16x16x32_bf16(a0, b0, d, 0, 0, 0);
    d = __builtin_amdgcn_mfma_f32_16x16x32_bf16(a1, b1, d, 0, 0, 0);
    dint[lt] = d;
  }

  // gated score matrix: G[t][l] = (l<=t) ? (C·(B dt)^T)[t][l]*exp(cum_t-cum_l) : 0
#pragma unroll
  for (int lt = 0; lt < 4; ++lt) {
    int r = lt * 16 + i;
    float dtv = dtS[r];
    const unsigned short* brow = &xp[(base + r) * 192 + 64];
    us8 bv0 = *(const us8*)&brow[q * 8];
    us8 bv1 = *(const us8*)&brow[32 + q * 8];
    union { unsigned short us[8]; short8 s8; } c0, c1;
#pragma unroll
    for (int j = 0; j < 8; ++j) {
      c0.us[j] = tobf(frombf(bv0[j]) * dtv);
      c1.us[j] = tobf(frombf(bv1[j]) * dtv);
    }
    f32x4 d = {0.f, 0.f, 0.f, 0.f};
    d = __builtin_amdgcn_mfma_f32_16x16x32_bf16(a0, c0.s8, d, 0, 0, 0);
    d = __builtin_amdgcn_mfma_f32_16x16x32_bf16(a1, c1.s8, d, 0, 0, 0);
#pragma unroll
    for (int r2 = 0; r2 < 4; ++r2) {
      int t = mt * 16 + q * 4 + r2;
      int l = lt * 16 + i;
      float g = (l <= t) ? d[r2] * expf(cumS[t] - cumS[l]) : 0.f;
      Gb[t][l] = tobf(g);
    }
  }

  short8 g0 = *(const short8*)&Gb[mt * 16 + i][q * 8];
  short8 g1 = *(const short8*)&Gb[mt * 16 + i][q * 8 + 32];
  float Dv = Dp[dir];
  float et4[4];
#pragma unroll
  for (int r2 = 0; r2 < 4; ++r2) et4[r2] = expf(cumS[mt * 16 + q * 4 + r2]);
  float yv[4][4];
  float rowss[4] = {0.f, 0.f, 0.f, 0.f};
#pragma unroll
  for (int lt = 0; lt < 4; ++lt) {
    const unsigned short* xrow = &xXp[(lt * 16 + i) * 64];
    short8 b0 = *(const short8*)&xrow[q * 8];
    short8 b1 = *(const short8*)&xrow[q * 8 + 32];
    f32x4 d = {0.f, 0.f, 0.f, 0.f};
    d = __builtin_amdgcn_mfma_f32_16x16x32_bf16(g0, b0, d, 0, 0, 0);
    d = __builtin_amdgcn_mfma_f32_16x16x32_bf16(g1, b1, d, 0, 0, 0);
    us4 zq = *(const us4*)&zT[(((long)dir * 64 + lt * 16 + i) * 8 + b) * 4096 +
                              (long)k * 64 + mt * 16 + q * 4];
    unsigned int xpk0 = *(const unsigned int*)&xrow[mt * 16 + q * 4];
    unsigned int xpk1 = *(const unsigned int*)&xrow[mt * 16 + q * 4 + 2];
    float xvr[4];
    xvr[0] = frombf((unsigned short)(xpk0 & 0xFFFFu));
    xvr[1] = frombf((unsigned short)(xpk0 >> 16));
    xvr[2] = frombf((unsigned short)(xpk1 & 0xFFFFu));
    xvr[3] = frombf((unsigned short)(xpk1 >> 16));
#pragma unroll
    for (int r2 = 0; r2 < 4; ++r2) {
      float y = d[r2] + et4[r2] * dint[lt][r2] + Dv * xvr[r2];
      float zv = frombf(zq[r2]);
      float v = y * siluf(zv);
      yv[lt][r2] = v;
      rowss[r2] += v * v;
    }
  }
#pragma unroll
  for (int m = 1; m < 16; m <<= 1) {
#pragma unroll
    for (int r2 = 0; r2 < 4; ++r2) rowss[r2] += __shfl_xor(rowss[r2], m);
  }
  float rscv[4];
#pragma unroll
  for (int r2 = 0; r2 < 4; ++r2)
    rscv[r2] = rsqrtf(rowss[r2] * (1.0f / 64.0f) + 1e-5f);
  // ynorm back into own stripe of Gb (same-wave r/w)
#pragma unroll
  for (int lt = 0; lt < 4; ++lt)
#pragma unroll
    for (int r2 = 0; r2 < 4; ++r2) {
      int t = mt * 16 + q * 4 + r2;
      int p = lt * 16 + i;
      Gb[t][p] = tobf(yv[lt][r2] * rscv[r2]);
    }

  short8 y0 = *(const short8*)&Gb[mt * 16 + i][q * 8];
  short8 y1 = *(const short8*)&Gb[mt * 16 + i][q * 8 + 32];
  unsigned short* s2x = dir ? s2b : s2a;
#pragma unroll
  for (int dt = 0; dt < 2; ++dt) {
    const unsigned short* wrow = &wnp[(dt * 16 + i) * 64];
    short8 b0 = *(const short8*)&wrow[q * 8];
    short8 b1 = *(const short8*)&wrow[q * 8 + 32];
    f32x4 d = {0.f, 0.f, 0.f, 0.f};
    d = __builtin_amdgcn_mfma_f32_16x16x32_bf16(y0, b0, d, 0, 0, 0);
    d = __builtin_amdgcn_mfma_f32_16x16x32_bf16(y1, b1, d, 0, 0, 0);
#pragma unroll
    for (int r2 = 0; r2 < 4; ++r2) {
      int tl = mt * 16 + q * 4 + r2;
      int l = k * 64 + tl;
      int lout = dir ? (4095 - l) : l;
      int dd = dt * 16 + i;
      s2x[((long)b * 4096 + lout) * 32 + dd] = tobf(d[r2]);
    }
  }
}

// K10: o3 = (s2a+s2b)@W — GEMM (bf16 in/out) + BN partials to scratch (no atomics).
__global__ void k_fcout(const unsigned short* __restrict__ s2a,
                        const unsigned short* __restrict__ s2b,
                        const float* __restrict__ w, unsigned short* __restrict__ o3,
                        float* __restrict__ part) {
  __shared__ float st[32][68];
  __shared__ float wt[32][64];
  int b = blockIdx.y, l0 = blockIdx.x * 64, cb = blockIdx.z * 64;
  int tid = threadIdx.x;
  {
    int d = tid & 31, l = tid >> 5;
    for (int si = 0; si < 8; ++si) {
      int ll = l + si * 8;
      long o = ((long)b * 4096 + l0 + ll) * 32 + d;
      st[d][ll] = frombf(s2a[o]) + frombf(s2b[o]);
    }
    int f4 = (tid & 15) * 4, r = tid >> 4;
    for (int si = 0; si < 2; ++si) {
      int rr = r + si * 16;
      *(float4*)&wt[rr][f4] = *(const float4*)&w[rr * 128 + cb + f4];
    }
  }
  __syncthreads();
  int tx = tid & 15, ty = tid >> 4;
  int c0 = tx * 4, t0 = ty * 4;
  float acc[4][4] = {};
  for (int k = 0; k < 32; ++k) {
    float4 xv = *(float4*)&st[k][c0];
    float4 wv = *(float4*)&wt[k][t0];
    float xa[4] = {xv.x, xv.y, xv.z, xv.w};
    float wa[4] = {wv.x, wv.y, wv.z, wv.w};
#pragma unroll
    for (int a = 0; a < 4; ++a)
#pragma unroll
      for (int q = 0; q < 4; ++q) acc[a][q] += wa[a] * xa[q];
  }
#pragma unroll
  for (int a = 0; a < 4; ++a) {
    us4 pk;
#pragma unroll
    for (int q = 0; q < 4; ++q) pk[q] = tobf(acc[a][q]);
    *(us4*)&o3[((long)b * 128 + cb + t0 + a) * 4096 + l0 + c0] = pk;
  }
  // ---- BN partial sums: reduce over the 16 l-lanes, store per-block partials ----
  float ssum[4], sqq[4];
#pragma unroll
  for (int a = 0; a < 4; ++a) {
    ssum[a] = acc[a][0] + acc[a][1] + acc[a][2] + acc[a][3];
    sqq[a] = acc[a][0] * acc[a][0] + acc[a][1] * acc[a][1] +
             acc[a][2] * acc[a][2] + acc[a][3] * acc[a][3];
  }
#pragma unroll
  for (int m = 1; m < 16; m <<= 1) {
#pragma unroll
    for (int a = 0; a < 4; ++a) {
      ssum[a] += __shfl_xor(ssum[a], m);
      sqq[a] += __shfl_xor(sqq[a], m);
    }
  }
  if (tx == 0) {
    int idx = b * 64 + blockIdx.x;   // 512 slots per channel
#pragma unroll
    for (int a = 0; a < 4; ++a) {
      int ch = cb + t0 + a;
      part[(long)ch * 512 + idx] = ssum[a];
      part[65536 + (long)ch * 512 + idx] = sqq[a];
    }
  }
}

// K11: reduce BN partials (128 blocks = 1 per channel). No atomics anywhere.
__global__ void k_bnred(const float* __restrict__ part, float* __restrict__ stats) {
  int ch = blockIdx.x, tid = threadIdx.x;
  float s = part[(long)ch * 512 + tid] + part[(long)ch * 512 + 256 + tid];
  float q = part[65536 + (long)ch * 512 + tid] +
            part[65536 + (long)ch * 512 + 256 + tid];
  for (int off = 32; off; off >>= 1) {
    s += __shfl_down(s, off);
    q += __shfl_down(q, off);
  }
  __shared__ float rs[4], rq[4];
  if ((tid & 63) == 0) { rs[tid >> 6] = s; rq[tid >> 6] = q; }
  __syncthreads();
  if (tid == 0) {
    stats[ch] = rs[0] + rs[1] + rs[2] + rs[3];
    stats[128 + ch] = rq[0] + rq[1] + rq[2] + rq[3];
  }
}

// K12: BN + conv4 + sigmoid + gated residual — MFMA bf16 (BN folded in staging).
__global__ __launch_bounds__(256) void k_final(const unsigned short* __restrict__ o3,
                                               const float* __restrict__ stats,
                                               const float* __restrict__ bng,
                                               const float* __restrict__ bnb,
                                               const unsigned short* __restrict__ wb,
                                               const float* __restrict__ bias,
                                               const float* __restrict__ x,
                                               float* __restrict__ out) {
  __shared__ unsigned short wT[64][140];
  __shared__ unsigned short aT[64][140];
  __shared__ float sc[128], sh[128];
  int b = blockIdx.y, l0 = blockIdx.x * 64, cb = blockIdx.z * 64;
  int tid = threadIdx.x, lane = tid & 63, mt = tid >> 6;
  int q = lane >> 4, i = lane & 15;
  if (tid < 128) {
    float mu = stats[tid] * (1.0f / 32768.0f);
    float var = stats[128 + tid] * (1.0f / 32768.0f) - mu * mu;
    float r = rsqrtf(var + 1e-5f);
    sc[tid] = r * bng[tid];
    sh[tid] = bnb[tid] - mu * r * bng[tid];
  }
  __syncthreads();
  int c4 = (tid & 15) * 4, k0 = (tid >> 4) * 2;
#pragma unroll
  for (int s = 0; s < 4; ++s) {
    int k = k0 + s * 32;
    us4 w0 = *(const us4*)&wb[k * 128 + cb + c4];
    us4 w1 = *(const us4*)&wb[(k + 1) * 128 + cb + c4];
#pragma unroll
    for (int j = 0; j < 4; ++j)
      *(unsigned int*)&wT[c4 + j][k] =
          (unsigned int)w0[j] | ((unsigned int)w1[j] << 16);
    us4 a0 = *(const us4*)&o3[((long)b * 128 + k) * 4096 + l0 + c4];
    us4 a1 = *(const us4*)&o3[((long)b * 128 + k + 1) * 4096 + l0 + c4];
    float sc0 = sc[k], sh0 = sh[k], sc1 = sc[k + 1], sh1 = sh[k + 1];
#pragma unroll
    for (int j = 0; j < 4; ++j) {
      *(unsigned int*)&aT[c4 + j][k] =
          pk2(fmaf(frombf(a0[j]), sc0, sh0), fmaf(frombf(a1[j]), sc1, sh1));
    }
  }
  __syncthreads();
  short8 af[4];
#pragma unroll
  for (int kk = 0; kk < 4; ++kk)
    af[kk] = ldfrag(&wT[mt * 16 + i][q * 8 + 32 * kk]);
  float bv[4];
#pragma unroll
  for (int r2 = 0; r2 < 4; ++r2) bv[r2] = bias[cb + 16 * mt + q * 4 + r2];
#pragma unroll
  for (int nt = 0; nt < 4; ++nt) {
    f32x4 d = {0.f, 0.f, 0.f, 0.f};
#pragma unroll
    for (int kk = 0; kk < 4; ++kk) {
      short8 bfr = ldfrag(&aT[nt * 16 + i][q * 8 + 32 * kk]);
      d = __builtin_amdgcn_mfma_f32_16x16x32_bf16(af[kk], bfr, d, 0, 0, 0);
    }
#pragma unroll
    for (int r2 = 0; r2 < 4; ++r2) {
      int c = 16 * mt + q * 4 + r2;
      long xi = ((long)b * 128 + cb + c) * 4096 + l0 + nt * 16 + i;
      float g = 1.0f / (1.0f + expf(-(d[r2] + bv[r2])));
      out[xi] = x[xi] * (1.0f + g);
    }
  }
}

extern "C" void kernel_launch(void* const* d_in, const int* in_sizes, int n_in,
                              void* d_out, int out_size, void* d_ws, size_t ws_size,
                              hipStream_t stream) {
  const float* x          = (const float*)d_in[0];
  const float* lin1_w     = (const float*)d_in[1];
  const float* lin1_b     = (const float*)d_in[2];
  const float* dw_w       = (const float*)d_in[3];
  const float* dw_b       = (const float*)d_in[4];
  const float* fc_in_w    = (const float*)d_in[5];
  const float* mam_in_w   = (const float*)d_in[6];
  const float* mam_conv_w = (const float*)d_in[7];
  const float* mam_conv_b = (const float*)d_in[8];
  const float* mam_dt_bias= (const float*)d_in[9];
  const float* mam_A_log  = (const float*)d_in[10];
  const float* mam_D      = (const float*)d_in[11];
  const float* mam_norm_w = (const float*)d_in[12];
  const float* mam_out_w  = (const float*)d_in[13];
  const float* fc_out_w   = (const float*)d_in[14];
  const float* bn_g       = (const float*)d_in[15];
  const float* bn_b       = (const float*)d_in[16];
  const float* conv4_w    = (const float*)d_in[17];
  const float* conv4_b    = (const float*)d_in[18];
  float* out = (float*)d_out;
  float* ws  = (float*)d_ws;

  unsigned short* o1h  = (unsigned short*)(ws + OFF_O1);
  unsigned short* sbuf = (unsigned short*)(ws + OFF_S);
  unsigned short* zTb  = (unsigned short*)(ws + OFF_Z);
  unsigned short* WTb  = (unsigned short*)(ws + OFF_WT);
  unsigned short* xbca = (unsigned short*)(ws + OFF_XBCA);
  float* dts  = ws + OFF_DTS;
  float* cum  = ws + OFF_CUM;
  unsigned short* Tbufh = (unsigned short*)(ws + OFF_T);
  unsigned short* Sprev = (unsigned short*)(ws + OFF_SPREV);
  unsigned short* s2a = (unsigned short*)(ws + OFF_S2A);
  unsigned short* s2b = (unsigned short*)(ws + OFF_S2B);
  float* bnst = ws + OFF_BN;
  unsigned short* xXb = (unsigned short*)(ws + OFF_XX);
  unsigned short* wb1 = (unsigned short*)(ws + OFF_WB1);
  unsigned short* wb4 = (unsigned short*)(ws + OFF_WB4);
  unsigned short* wnb = (unsigned short*)(ws + OFF_WN);
  unsigned short* o3h = (unsigned short*)(ws + OFF_O3);
  float* part = ws + OFF_T;   // Tbuf dead after k_scan; reuse for BN partials

  k_prepc<<<6, 256, 0, stream>>>(lin1_w, conv4_w, mam_norm_w, mam_out_w, mam_in_w,
                                 wb1, wb4, wnb, WTb);
  k_lin1<<<dim3(64, 8, 2), 256, 0, stream>>>(x, wb1, lin1_b, o1h);
  k_dwfc<<<dim3(64, 8), 256, 0, stream>>>(o1h, dw_w, dw_b, fc_in_w, sbuf);
  k_inprojconv<<<dim3(64, 8, 2), 256, 0, stream>>>(sbuf, WTb, mam_conv_w, mam_conv_b,
                                                   mam_dt_bias, mam_A_log,
                                                   zTb, xbca, xXb, dts, cum, Tbufh);
  k_scan<<<256, 256, 0, stream>>>(Tbufh, cum, Sprev);
  k_chunkYout<<<dim3(512, 2), 256, 0, stream>>>(xbca, dts, cum, Sprev, mam_D, zTb,
                                                xXb, wnb, s2a, s2b);
  k_fcout<<<dim3(64, 8, 2), 256, 0, stream>>>(s2a, s2b, fc_out_w, o3h, part);
  k_bnred<<<128, 256, 0, stream>>>(part, bnst);
  k_final<<<dim3(64, 8, 2), 256, 0, stream>>>(o3h, bnst, bn_g, bn_b, wb4, conv4_b, x, out);
}

// Round 13
// 199.520 us; speedup vs baseline: 1.1296x; 1.1296x over previous
//
#include <hip/hip_runtime.h>
#include <math.h>

// Problem constants
constexpr int Bn = 8, Cn = 128, Ln = 4096;

// Workspace layout (float offsets). o1/o2/o3, z, s, xbca, Sprev, T, s2 stored bf16.
constexpr size_t OFF_O1   = 0;          // bf16 o1; later bf16 o3 (aliased)
constexpr size_t OFF_O2   = 4194304;    // bf16
constexpr size_t OFF_S    = 8388608;    // bf16: 8*4096*32 ushort
constexpr size_t OFF_Z    = 9437184;    // bf16 zT[dir][p=64][b=8][l=4096]
constexpr size_t OFF_WT   = 11534336;   // bf16 WT[dir][n=272][k=32]
constexpr size_t OFF_XBCA = 13631488;   // bf16: 2 dirs x 6,291,456 ushort
constexpr size_t OFF_DTS  = 26214400;
constexpr size_t OFF_CUM  = 26279936;
constexpr size_t OFF_T    = 26345472;   // bf16 2 dirs x 2,097,152; reused for BN partials
constexpr size_t OFF_SPREV= 30539776;   // bf16: 2 dirs x 2,097,152 ushort
constexpr size_t OFF_S2A  = 34734080;   // bf16
constexpr size_t OFF_S2B  = 35782656;   // bf16
constexpr size_t OFF_BN   = 36831232;
constexpr size_t OFF_O3   = 0;

constexpr long XSTRIDE_H = 6291456;   // ushort elements per dir
constexpr long TSTRIDE = 2097152;     // element stride per dir (u16 for T and Sprev)

typedef __attribute__((ext_vector_type(8))) short short8;
typedef __attribute__((ext_vector_type(4))) float f32x4;
typedef __attribute__((ext_vector_type(4))) unsigned short us4;
typedef __attribute__((ext_vector_type(8))) unsigned short us8;

__device__ __forceinline__ float siluf(float v) { return v / (1.0f + expf(-v)); }

__device__ __forceinline__ unsigned short tobf(float f) {
  unsigned int u = __float_as_uint(f);
  u += 0x7FFFu + ((u >> 16) & 1u);     // RNE
  return (unsigned short)(u >> 16);
}

__device__ __forceinline__ float frombf(unsigned short u) {
  return __uint_as_float(((unsigned int)u) << 16);
}

__device__ __forceinline__ unsigned int pk2(float a, float b) {
  return (unsigned int)tobf(a) | ((unsigned int)tobf(b) << 16);
}

// 8 consecutive bf16 from LDS via 4 dword reads (>=4B-aligned offsets)
__device__ __forceinline__ short8 ldfrag(const unsigned short* p) {
  union { unsigned int u[4]; short8 s; } cv;
  cv.u[0] = *(const unsigned int*)(p);
  cv.u[1] = *(const unsigned int*)(p + 2);
  cv.u[2] = *(const unsigned int*)(p + 4);
  cv.u[3] = *(const unsigned int*)(p + 6);
  return cv.s;
}

// K1: o1[b,c,l] = sum_k x[b,k,l]*w[k,c] + bias[c] — MFMA bf16, K=128. bf16 out.
__global__ __launch_bounds__(256) void k_lin1(const float* __restrict__ x,
                                              const float* __restrict__ w,
                                              const float* __restrict__ bias,
                                              unsigned short* __restrict__ o1) {
  __shared__ unsigned short wT[64][140];
  __shared__ unsigned short xT[64][140];
  int b = blockIdx.y, l0 = blockIdx.x * 64, cb = blockIdx.z * 64;
  int tid = threadIdx.x, lane = tid & 63, mt = tid >> 6;
  int q = lane >> 4, i = lane & 15;
  int c4 = (tid & 15) * 4, k0 = (tid >> 4) * 2;
#pragma unroll
  for (int s = 0; s < 4; ++s) {
    int k = k0 + s * 32;
    float4 w0 = *(const float4*)&w[k * 128 + cb + c4];
    float4 w1 = *(const float4*)&w[(k + 1) * 128 + cb + c4];
    *(unsigned int*)&wT[c4 + 0][k] = pk2(w0.x, w1.x);
    *(unsigned int*)&wT[c4 + 1][k] = pk2(w0.y, w1.y);
    *(unsigned int*)&wT[c4 + 2][k] = pk2(w0.z, w1.z);
    *(unsigned int*)&wT[c4 + 3][k] = pk2(w0.w, w1.w);
    float4 x0 = *(const float4*)&x[((long)b * 128 + k) * 4096 + l0 + c4];
    float4 x1 = *(const float4*)&x[((long)b * 128 + k + 1) * 4096 + l0 + c4];
    *(unsigned int*)&xT[c4 + 0][k] = pk2(x0.x, x1.x);
    *(unsigned int*)&xT[c4 + 1][k] = pk2(x0.y, x1.y);
    *(unsigned int*)&xT[c4 + 2][k] = pk2(x0.z, x1.z);
    *(unsigned int*)&xT[c4 + 3][k] = pk2(x0.w, x1.w);
  }
  __syncthreads();
  short8 af[4];
#pragma unroll
  for (int kk = 0; kk < 4; ++kk)
    af[kk] = ldfrag(&wT[mt * 16 + i][q * 8 + 32 * kk]);
  float bv[4];
#pragma unroll
  for (int r2 = 0; r2 < 4; ++r2) bv[r2] = bias[cb + 16 * mt + q * 4 + r2];
#pragma unroll
  for (int nt = 0; nt < 4; ++nt) {
    f32x4 d = {0.f, 0.f, 0.f, 0.f};
#pragma unroll
    for (int kk = 0; kk < 4; ++kk) {
      short8 bfr = ldfrag(&xT[nt * 16 + i][q * 8 + 32 * kk]);
      d = __builtin_amdgcn_mfma_f32_16x16x32_bf16(af[kk], bfr, d, 0, 0, 0);
    }
#pragma unroll
    for (int r2 = 0; r2 < 4; ++r2) {
      int c = 16 * mt + q * 4 + r2;
      o1[((long)b * 128 + cb + c) * 4096 + l0 + nt * 16 + i] = tobf(d[r2] + bv[r2]);
    }
  }
}

// K2: depthwise 3x3 SAME + bias + silu. bf16 in/out, f32 LDS plane + math.
__global__ void k_dw(const unsigned short* __restrict__ o1,
                     const float* __restrict__ wgt,
                     const float* __restrict__ bias, unsigned short* __restrict__ o2) {
  __shared__ float p[4096];
  int bc = blockIdx.x, c = bc & 127, tid = threadIdx.x;
  const unsigned short* src = o1 + (long)bc * 4096;
#pragma unroll
  for (int s4 = 0; s4 < 2; ++s4) {
    int off = s4 * 2048 + tid * 8;
    us8 v = *(const us8*)&src[off];
#pragma unroll
    for (int j = 0; j < 8; ++j) p[off + j] = frombf(v[j]);
  }
  float wr[9];
#pragma unroll
  for (int j = 0; j < 9; ++j) wr[j] = wgt[c * 9 + j];
  float bv = bias[c];
  __syncthreads();
  int wg = tid & 15, hs = tid >> 4;
  int w0 = wg * 4, h0 = hs * 4;
  float in[6][6];
#pragma unroll
  for (int ri = 0; ri < 6; ++ri) {
    int h = h0 - 1 + ri;
    if (h < 0 || h > 63) {
#pragma unroll
      for (int ci = 0; ci < 6; ++ci) in[ri][ci] = 0.f;
    } else {
      float4 cc = *(float4*)&p[h * 64 + w0];
      in[ri][1] = cc.x; in[ri][2] = cc.y; in[ri][3] = cc.z; in[ri][4] = cc.w;
      in[ri][0] = (w0 > 0) ? p[h * 64 + w0 - 1] : 0.f;
      in[ri][5] = (w0 < 60) ? p[h * 64 + w0 + 4] : 0.f;
    }
  }
#pragma unroll
  for (int r = 0; r < 4; ++r) {
    us4 oc;
#pragma unroll
    for (int q = 0; q < 4; ++q) {
      float acc = bv;
#pragma unroll
      for (int dh = 0; dh < 3; ++dh)
#pragma unroll
        for (int dq = 0; dq < 3; ++dq)
          acc += in[r + dh][q + dq] * wr[dh * 3 + dq];
      oc[q] = tobf(siluf(acc));
    }
    *(us4*)&o2[(long)bc * 4096 + (h0 + r) * 64 + w0] = oc;
  }
}

// K3: s[b,l,d] = sum_c o2[b,c,l]*w[c,d] (d<32). bf16 in/out. Folds prepW.
__global__ void k_fcin(const unsigned short* __restrict__ o2, const float* __restrict__ w,
                       unsigned short* __restrict__ sb,
                       const float* __restrict__ Win, unsigned short* __restrict__ WT) {
  __shared__ float xt[128][64];
  __shared__ float wt[128][32];
  int b = blockIdx.y, l0 = blockIdx.x * 64;
  int tid = threadIdx.x;
  int f4 = (tid & 15) * 4, r0 = tid >> 4;
#pragma unroll
  for (int st = 0; st < 8; ++st) {
    int r = r0 + st * 16;
    us4 v = *(const us4*)&o2[((long)b * 128 + r) * 4096 + l0 + f4];
#pragma unroll
    for (int j = 0; j < 4; ++j) xt[r][f4 + j] = frombf(v[j]);
  }
  int f4w = (tid & 7) * 4, rw = tid >> 3;
#pragma unroll
  for (int st = 0; st < 4; ++st) {
    int r = rw + st * 32;
    *(float4*)&wt[r][f4w] = *(const float4*)&w[r * 32 + f4w];
  }
  __syncthreads();
  int tx = tid & 15, ty = tid >> 4;
  int c0 = tx * 4, d0 = ty * 2;
  float acc[2][4] = {};
  for (int k = 0; k < 128; ++k) {
    float4 xv = *(float4*)&xt[k][c0];
    float2 wv = *(float2*)&wt[k][d0];
    float xa[4] = {xv.x, xv.y, xv.z, xv.w};
#pragma unroll
    for (int q = 0; q < 4; ++q) {
      acc[0][q] += wv.x * xa[q];
      acc[1][q] += wv.y * xa[q];
    }
  }
#pragma unroll
  for (int q = 0; q < 4; ++q) {
    long ob = ((long)b * 4096 + l0 + c0 + q) * 32 + d0;
    *(unsigned int*)&sb[ob] = pk2(acc[0][q], acc[1][q]);
  }
  // ---- folded prepW: WT[dir][n(272 padded)][k(32)], zeros n>=257 ----
  if (blockIdx.y == 0 && blockIdx.x < 2) {
    int dir = blockIdx.x;
    for (int idx = tid; idx < 272 * 32; idx += 256) {
      int n = idx >> 5, kk = idx & 31;
      float v = (n < 257) ? Win[dir * 32 * 257 + kk * 257 + n] : 0.f;
      WT[dir * 8704 + idx] = tobf(v);
    }
  }
}

// K4: in_proj (MFMA bf16, K=32) + causal conv1d + silu + dt softplus + cum
//     + fused chunk summary T[p][n] (MFMA bf16, T stored bf16).
// fXf removed: post-conv X stored bf16 IN-PLACE into xbcT rows 0..63 (trailing
// write, same as B path); scale phase is an in-place u32 RMW (2-way banks, free).
__global__ __launch_bounds__(256) void k_inprojconv(
    const unsigned short* __restrict__ sb, const unsigned short* __restrict__ WT,
    const float* __restrict__ conv_w, const float* __restrict__ conv_b,
    const float* __restrict__ dt_bias, const float* __restrict__ A_log,
    unsigned short* __restrict__ zT, unsigned short* __restrict__ xbca,
    float* __restrict__ dts, float* __restrict__ cum,
    unsigned short* __restrict__ Tg) {
  __shared__ unsigned short xbcT[192][82];   // [channel][t], pitch 82: conflict-free
  __shared__ float dtL[64];                  // raw dt MFMA outputs
  __shared__ float dtsS[64], cumSS[64], fL[64];
  int dir = blockIdx.z, b = blockIdx.y, l0 = blockIdx.x * 64;
  int tid = threadIdx.x, lane = tid & 63, mt = tid >> 6;
  int q = lane >> 4, i = lane & 15;
  long rowbase = (long)b * 4096 + l0;
  const unsigned short* W = WT + (long)dir * 8704;
  const short8 zfrag = {0, 0, 0, 0, 0, 0, 0, 0};

  if (mt == 0) {
    // ---- z columns (n 0..63) + dt column, l0-aligned rows ----
    short8 afr[4];
#pragma unroll
    for (int rt = 0; rt < 4; ++rt) {
      int l = l0 + 16 * rt + i;
      int lsrc = dir ? (4095 - l) : l;
      afr[rt] = *(const short8*)&sb[((long)b * 4096 + lsrc) * 32 + q * 8];
    }
#pragma unroll
    for (int ct = 0; ct < 4; ++ct) {
      int n = 16 * ct + i;
      short8 bfr = *(const short8*)&W[n * 32 + q * 8];
      unsigned short* zrow = zT + (((long)dir * 64 + n) * 8 + b) * 4096 + l0 + q * 4;
#pragma unroll
      for (int rt = 0; rt < 4; ++rt) {
        f32x4 d = {0.f, 0.f, 0.f, 0.f};
        d = __builtin_amdgcn_mfma_f32_16x16x32_bf16(afr[rt], bfr, d, 0, 0, 0);
        us4 pk;
        pk[0] = tobf(d[0]); pk[1] = tobf(d[1]);
        pk[2] = tobf(d[2]); pk[3] = tobf(d[3]);
        *(us4*)&zrow[16 * rt] = pk;
      }
    }
    {
      short8 bfr = *(const short8*)&W[(256 + i) * 32 + q * 8];
#pragma unroll
      for (int rt = 0; rt < 4; ++rt) {
        f32x4 d = {0.f, 0.f, 0.f, 0.f};
        d = __builtin_amdgcn_mfma_f32_16x16x32_bf16(afr[rt], bfr, d, 0, 0, 0);
        if (i == 0) {
#pragma unroll
          for (int r2 = 0; r2 < 4; ++r2) dtL[16 * rt + q * 4 + r2] = d[r2];
        }
      }
    }
  } else {
    // ---- xbc columns (n 64..255), rows with -3 conv halo ----
    short8 afr[5];
#pragma unroll
    for (int rt = 0; rt < 5; ++rt) {
      int l = l0 - 3 + 16 * rt + i;
      if (l >= 0 && l < 4096) {
        int lsrc = dir ? (4095 - l) : l;
        afr[rt] = *(const short8*)&sb[((long)b * 4096 + lsrc) * 32 + q * 8];
      } else {
        afr[rt] = zfrag;
      }
    }
#pragma unroll
    for (int cti = 0; cti < 4; ++cti) {
      int n = 16 * (mt * 4 + cti) + i;
      short8 bfr = *(const short8*)&W[n * 32 + q * 8];
      int cc = n - 64;
#pragma unroll
      for (int rt = 0; rt < 5; ++rt) {
        f32x4 d = {0.f, 0.f, 0.f, 0.f};
        d = __builtin_amdgcn_mfma_f32_16x16x32_bf16(afr[rt], bfr, d, 0, 0, 0);
        int rr0 = 16 * rt + q * 4;
        unsigned int p0 = (unsigned int)tobf(d[0]) | ((unsigned int)tobf(d[1]) << 16);
        unsigned int p1 = (unsigned int)tobf(d[2]) | ((unsigned int)tobf(d[3]) << 16);
        *(unsigned int*)&xbcT[cc][rr0] = p0;
        *(unsigned int*)&xbcT[cc][rr0 + 2] = p1;
      }
    }
  }
  __syncthreads();

  if (tid < 192) {
    int c = tid;
    float cw0 = conv_w[dir * 768 + c * 4 + 0];
    float cw1 = conv_w[dir * 768 + c * 4 + 1];
    float cw2 = conv_w[dir * 768 + c * 4 + 2];
    float cw3 = conv_w[dir * 768 + c * 4 + 3];
    float cb2 = conv_b[dir * 192 + c];
    unsigned short* xp = xbca + (long)dir * XSTRIDE_H;
    float win0 = 0.f, win1 = 0.f, win2 = 0.f, win3 = 0.f;
    for (int rp = 0; rp < 34; ++rp) {
      unsigned int pk = *(const unsigned int*)&xbcT[c][rp * 2];
      float a0 = frombf((unsigned short)(pk & 0xFFFFu));
      float a1 = frombf((unsigned short)(pk >> 16));
      int rr = rp * 2;
      win0 = win1; win1 = win2; win2 = win3; win3 = a0;
      if (rr >= 3 && rr <= 66) {
        float acc = cb2 + win0 * cw0 + win1 * cw1 + win2 * cw2 + win3 * cw3;
        float sv = siluf(acc);
        int t = rr - 3;
        xp[(rowbase + t) * 192 + c] = tobf(sv);
        if (c < 128) xbcT[c][t] = tobf(sv);   // X and B rows, trailing in-place write
      }
      win0 = win1; win1 = win2; win2 = win3; win3 = a1;
      if (rr + 1 >= 3 && rr + 1 <= 66) {
        float acc = cb2 + win0 * cw0 + win1 * cw1 + win2 * cw2 + win3 * cw3;
        float sv = siluf(acc);
        int t = rr - 2;
        xp[(rowbase + t) * 192 + c] = tobf(sv);
        if (c < 128) xbcT[c][t] = tobf(sv);
      }
    }
  } else {
    int ln = tid - 192;
    float v = dtL[ln] + dt_bias[dir];
    float sp = (v > 20.f) ? v : log1pf(expf(v));
    dts[dir * 32768 + rowbase + ln] = sp;
    dtsS[ln] = sp;
    float cd = -expf(A_log[dir]) * sp;
#pragma unroll
    for (int off = 1; off < 64; off <<= 1) {
      float u = __shfl_up(cd, off);
      if (ln >= off) cd += u;
    }
    cum[dir * 32768 + rowbase + ln] = cd;
    cumSS[ln] = cd;
  }
  __syncthreads();

  if (tid < 64) fL[tid] = expf(cumSS[63] - cumSS[tid]) * dtsS[tid];
  __syncthreads();

  // scale phase: xbcT rows 0..63 <- tobf(frombf(xbcT) * fL), in-place u32 RMW
  {
    int c = tid & 63, tb2 = (tid >> 6) * 16;
#pragma unroll
    for (int j = 0; j < 8; ++j) {
      int t = tb2 + 2 * j;
      unsigned int pk = *(const unsigned int*)&xbcT[c][t];
      float v0 = frombf((unsigned short)(pk & 0xFFFFu));
      float v1 = frombf((unsigned short)(pk >> 16));
      unsigned int po = (unsigned int)tobf(v0 * fL[t]) |
                        ((unsigned int)tobf(v1 * fL[t + 1]) << 16);
      *(unsigned int*)&xbcT[c][t] = po;
    }
  }
  __syncthreads();

  // MFMA-T: T[p][n] = sum_t fX[p][t] * B[n][t], K=64 (two K=32 MFMAs), bf16 out
  {
    short8 a0 = ldfrag(&xbcT[mt * 16 + i][q * 8]);
    short8 a1 = ldfrag(&xbcT[mt * 16 + i][q * 8 + 32]);
    unsigned short* Tp = Tg + (long)dir * TSTRIDE + ((long)(b * 64 + blockIdx.x)) * 4096;
#pragma unroll
    for (int nt = 0; nt < 4; ++nt) {
      short8 b0 = ldfrag(&xbcT[64 + nt * 16 + i][q * 8]);
      short8 b1 = ldfrag(&xbcT[64 + nt * 16 + i][q * 8 + 32]);
      f32x4 d = {0.f, 0.f, 0.f, 0.f};
      d = __builtin_amdgcn_mfma_f32_16x16x32_bf16(a0, b0, d, 0, 0, 0);
      d = __builtin_amdgcn_mfma_f32_16x16x32_bf16(a1, b1, d, 0, 0, 0);
#pragma unroll
      for (int r2 = 0; r2 < 4; ++r2)
        Tp[(mt * 16 + q * 4 + r2) * 64 + nt * 16 + i] = tobf(d[r2]);
    }
  }
}

// K7: inter-chunk state scan — 256 blocks (full CU coverage), bf16 T in, bf16 out.
__global__ void k_scan(const unsigned short* __restrict__ T, const float* __restrict__ cum,
                       unsigned short* __restrict__ Sprev) {
  __shared__ float E[64];
  int blk = blockIdx.x;            // 256 blocks
  int dirb = blk >> 4;             // dir*8 + b
  int dir = dirb >> 3, b = dirb & 7;
  int pn = (blk & 15) * 256 + threadIdx.x;
  const float* cp = cum + dir * 32768 + b * 4096;
  if (threadIdx.x < 64) E[threadIdx.x] = expf(cp[threadIdx.x * 64 + 63]);
  __syncthreads();
  const unsigned short* Tp = T + (long)dir * TSTRIDE + (long)b * 262144 + pn;
  unsigned short* Sp = Sprev + (long)dir * TSTRIDE + (long)b * 262144 + pn;
  float s0 = 0.f;
  float tb[16];
#pragma unroll
  for (int j = 0; j < 16; ++j) tb[j] = frombf(Tp[(long)j * 4096]);
  for (int kc = 0; kc < 4; ++kc) {
    float tn[16];
    if (kc < 3) {
#pragma unroll
      for (int j = 0; j < 16; ++j)
        tn[j] = frombf(Tp[(long)(kc * 16 + 16 + j) * 4096]);
    }
#pragma unroll
    for (int j = 0; j < 16; ++j) {
      int k = kc * 16 + j;
      Sp[(long)k * 4096] = tobf(s0);
      s0 = fmaf(E[k], s0, tb[j]);
    }
    if (kc < 3) {
#pragma unroll
      for (int j = 0; j < 16; ++j) tb[j] = tn[j];
    }
  }
}

// K8: per-chunk Y + gate + RMSNorm + out-proj — MFMA bf16.
// C / Sprev / B*dt fragments loaded DIRECTLY from global (16B-contiguous rows);
// only the true transpose (Xt) + cross-wave tiles (Gb, WnT) in LDS. One barrier.
__global__ __launch_bounds__(256) void k_chunkYout(
    const unsigned short* __restrict__ xbca, const float* __restrict__ dts,
    const float* __restrict__ cum, const unsigned short* __restrict__ Sprev,
    const float* __restrict__ Dp, const unsigned short* __restrict__ zT,
    const float* __restrict__ normw, const float* __restrict__ Wout,
    unsigned short* __restrict__ s2a, unsigned short* __restrict__ s2b) {
  __shared__ unsigned short Xt[64][68];   // X transposed [p][t]
  __shared__ unsigned short Gb[64][72];   // gated G, then ynorm
  __shared__ unsigned short WnT[32][66];
  __shared__ float cumS[64], dtS[64];
  int dir = blockIdx.y;
  int bk = blockIdx.x, b = bk >> 6, k = bk & 63;
  int tid = threadIdx.x, lane = tid & 63, mt = tid >> 6;
  int q = lane >> 4, i = lane & 15;
  const unsigned short* xp = xbca + (long)dir * XSTRIDE_H;
  const float* dtp = dts + dir * 32768;
  const float* cp = cum + dir * 32768;
  const unsigned short* Sp = Sprev + (long)dir * TSTRIDE;
  long base = (long)b * 4096 + (long)k * 64;

  // ---- stage: Xt via row-reads + transposed LDS writes; WnT; cum/dt ----
  {
    int s = tid >> 2, c0 = (tid & 3) * 16;
    us8 v0 = *(const us8*)&xp[(base + s) * 192 + c0];
    us8 v1 = *(const us8*)&xp[(base + s) * 192 + c0 + 8];
#pragma unroll
    for (int j = 0; j < 8; ++j) Xt[c0 + j][s] = v0[j];
#pragma unroll
    for (int j = 0; j < 8; ++j) Xt[c0 + 8 + j][s] = v1[j];
  }
  for (int idx = tid; idx < 2048; idx += 256) {
    int p = idx >> 5, d = idx & 31;
    WnT[d][p] = tobf(normw[dir * 64 + p] * Wout[(long)dir * 2048 + p * 32 + d]);
  }
  if (tid < 64) { cumS[tid] = cp[base + tid]; dtS[tid] = dtp[base + tid]; }
  __syncthreads();

  // C fragments direct from global (row base+mt*16+i, cols 128+q*8 / 160+q*8)
  const unsigned short* crow = &xp[(base + mt * 16 + i) * 192];
  short8 a0 = *(const short8*)&crow[128 + q * 8];
  short8 a1 = *(const short8*)&crow[160 + q * 8];

  // inter-chunk contribution: dint = C · Sprev (B-frags direct from global)
  f32x4 dint[4];
#pragma unroll
  for (int lt = 0; lt < 4; ++lt) {
    const unsigned short* sp8 = &Sp[(long)bk * 4096 + (lt * 16 + i) * 64 + q * 8];
    short8 b0 = *(const short8*)sp8;
    short8 b1 = *(const short8*)(sp8 + 32);
    f32x4 d = {0.f, 0.f, 0.f, 0.f};
    d = __builtin_amdgcn_mfma_f32_16x16x32_bf16(a0, b0, d, 0, 0, 0);
    d = __builtin_amdgcn_mfma_f32_16x16x32_bf16(a1, b1, d, 0, 0, 0);
    dint[lt] = d;
  }

  // gated score matrix: G[t][l] = (l<=t) ? (C·(B dt)^T)[t][l]*exp(cum_t-cum_l) : 0
#pragma unroll
  for (int lt = 0; lt < 4; ++lt) {
    int r = lt * 16 + i;
    float dtv = dtS[r];
    const unsigned short* brow = &xp[(base + r) * 192 + 64];
    us8 bv0 = *(const us8*)&brow[q * 8];
    us8 bv1 = *(const us8*)&brow[32 + q * 8];
    union { unsigned short us[8]; short8 s8; } c0, c1;
#pragma unroll
    for (int j = 0; j < 8; ++j) {
      c0.us[j] = tobf(frombf(bv0[j]) * dtv);
      c1.us[j] = tobf(frombf(bv1[j]) * dtv);
    }
    f32x4 d = {0.f, 0.f, 0.f, 0.f};
    d = __builtin_amdgcn_mfma_f32_16x16x32_bf16(a0, c0.s8, d, 0, 0, 0);
    d = __builtin_amdgcn_mfma_f32_16x16x32_bf16(a1, c1.s8, d, 0, 0, 0);
#pragma unroll
    for (int r2 = 0; r2 < 4; ++r2) {
      int t = mt * 16 + q * 4 + r2;
      int l = lt * 16 + i;
      float g = (l <= t) ? d[r2] * expf(cumS[t] - cumS[l]) : 0.f;
      Gb[t][l] = tobf(g);
    }
  }

  short8 g0 = *(const short8*)&Gb[mt * 16 + i][q * 8];
  short8 g1 = *(const short8*)&Gb[mt * 16 + i][q * 8 + 32];
  float Dv = Dp[dir];
  float et4[4];
#pragma unroll
  for (int r2 = 0; r2 < 4; ++r2) et4[r2] = expf(cumS[mt * 16 + q * 4 + r2]);
  float yv[4][4];
  float rowss[4] = {0.f, 0.f, 0.f, 0.f};
#pragma unroll
  for (int lt = 0; lt < 4; ++lt) {
    short8 b0 = ldfrag(&Xt[lt * 16 + i][q * 8]);
    short8 b1 = ldfrag(&Xt[lt * 16 + i][q * 8 + 32]);
    f32x4 d = {0.f, 0.f, 0.f, 0.f};
    d = __builtin_amdgcn_mfma_f32_16x16x32_bf16(g0, b0, d, 0, 0, 0);
    d = __builtin_amdgcn_mfma_f32_16x16x32_bf16(g1, b1, d, 0, 0, 0);
    us4 zq = *(const us4*)&zT[(((long)dir * 64 + lt * 16 + i) * 8 + b) * 4096 +
                              (long)k * 64 + mt * 16 + q * 4];
    unsigned int xpk0 = *(const unsigned int*)&Xt[lt * 16 + i][mt * 16 + q * 4];
    unsigned int xpk1 = *(const unsigned int*)&Xt[lt * 16 + i][mt * 16 + q * 4 + 2];
    float xvr[4];
    xvr[0] = frombf((unsigned short)(xpk0 & 0xFFFFu));
    xvr[1] = frombf((unsigned short)(xpk0 >> 16));
    xvr[2] = frombf((unsigned short)(xpk1 & 0xFFFFu));
    xvr[3] = frombf((unsigned short)(xpk1 >> 16));
#pragma unroll
    for (int r2 = 0; r2 < 4; ++r2) {
      float y = d[r2] + et4[r2] * dint[lt][r2] + Dv * xvr[r2];
      float zv = frombf(zq[r2]);
      float v = y * siluf(zv);
      yv[lt][r2] = v;
      rowss[r2] += v * v;
    }
  }
#pragma unroll
  for (int m = 1; m < 16; m <<= 1) {
#pragma unroll
    for (int r2 = 0; r2 < 4; ++r2) rowss[r2] += __shfl_xor(rowss[r2], m);
  }
  float rscv[4];
#pragma unroll
  for (int r2 = 0; r2 < 4; ++r2)
    rscv[r2] = rsqrtf(rowss[r2] * (1.0f / 64.0f) + 1e-5f);
  // ynorm back into own stripe of Gb (same-wave r/w)
#pragma unroll
  for (int lt = 0; lt < 4; ++lt)
#pragma unroll
    for (int r2 = 0; r2 < 4; ++r2) {
      int t = mt * 16 + q * 4 + r2;
      int p = lt * 16 + i;
      Gb[t][p] = tobf(yv[lt][r2] * rscv[r2]);
    }

  short8 y0 = *(const short8*)&Gb[mt * 16 + i][q * 8];
  short8 y1 = *(const short8*)&Gb[mt * 16 + i][q * 8 + 32];
  unsigned short* s2x = dir ? s2b : s2a;
#pragma unroll
  for (int dt = 0; dt < 2; ++dt) {
    short8 b0 = ldfrag(&WnT[dt * 16 + i][q * 8]);
    short8 b1 = ldfrag(&WnT[dt * 16 + i][q * 8 + 32]);
    f32x4 d = {0.f, 0.f, 0.f, 0.f};
    d = __builtin_amdgcn_mfma_f32_16x16x32_bf16(y0, b0, d, 0, 0, 0);
    d = __builtin_amdgcn_mfma_f32_16x16x32_bf16(y1, b1, d, 0, 0, 0);
#pragma unroll
    for (int r2 = 0; r2 < 4; ++r2) {
      int tl = mt * 16 + q * 4 + r2;
      int l = k * 64 + tl;
      int lout = dir ? (4095 - l) : l;
      int dd = dt * 16 + i;
      s2x[((long)b * 4096 + lout) * 32 + dd] = tobf(d[r2]);
    }
  }
}

// K10: o3 = (s2a+s2b)@W — GEMM (bf16 in/out) + BN partials to scratch (no atomics).
__global__ void k_fcout(const unsigned short* __restrict__ s2a,
                        const unsigned short* __restrict__ s2b,
                        const float* __restrict__ w, unsigned short* __restrict__ o3,
                        float* __restrict__ part) {
  __shared__ float st[32][68];
  __shared__ float wt[32][64];
  int b = blockIdx.y, l0 = blockIdx.x * 64, cb = blockIdx.z * 64;
  int tid = threadIdx.x;
  {
    int d = tid & 31, l = tid >> 5;
    for (int si = 0; si < 8; ++si) {
      int ll = l + si * 8;
      long o = ((long)b * 4096 + l0 + ll) * 32 + d;
      st[d][ll] = frombf(s2a[o]) + frombf(s2b[o]);
    }
    int f4 = (tid & 15) * 4, r = tid >> 4;
    for (int si = 0; si < 2; ++si) {
      int rr = r + si * 16;
      *(float4*)&wt[rr][f4] = *(const float4*)&w[rr * 128 + cb + f4];
    }
  }
  __syncthreads();
  int tx = tid & 15, ty = tid >> 4;
  int c0 = tx * 4, t0 = ty * 4;
  float acc[4][4] = {};
  for (int k = 0; k < 32; ++k) {
    float4 xv = *(float4*)&st[k][c0];
    float4 wv = *(float4*)&wt[k][t0];
    float xa[4] = {xv.x, xv.y, xv.z, xv.w};
    float wa[4] = {wv.x, wv.y, wv.z, wv.w};
#pragma unroll
    for (int a = 0; a < 4; ++a)
#pragma unroll
      for (int q = 0; q < 4; ++q) acc[a][q] += wa[a] * xa[q];
  }
#pragma unroll
  for (int a = 0; a < 4; ++a) {
    us4 pk;
#pragma unroll
    for (int q = 0; q < 4; ++q) pk[q] = tobf(acc[a][q]);
    *(us4*)&o3[((long)b * 128 + cb + t0 + a) * 4096 + l0 + c0] = pk;
  }
  // ---- BN partial sums: reduce over the 16 l-lanes, store per-block partials ----
  float ssum[4], sqq[4];
#pragma unroll
  for (int a = 0; a < 4; ++a) {
    ssum[a] = acc[a][0] + acc[a][1] + acc[a][2] + acc[a][3];
    sqq[a] = acc[a][0] * acc[a][0] + acc[a][1] * acc[a][1] +
             acc[a][2] * acc[a][2] + acc[a][3] * acc[a][3];
  }
#pragma unroll
  for (int m = 1; m < 16; m <<= 1) {
#pragma unroll
    for (int a = 0; a < 4; ++a) {
      ssum[a] += __shfl_xor(ssum[a], m);
      sqq[a] += __shfl_xor(sqq[a], m);
    }
  }
  if (tx == 0) {
    int idx = b * 64 + blockIdx.x;   // 512 slots per channel
#pragma unroll
    for (int a = 0; a < 4; ++a) {
      int ch = cb + t0 + a;
      part[(long)ch * 512 + idx] = ssum[a];
      part[65536 + (long)ch * 512 + idx] = sqq[a];
    }
  }
}

// K11: reduce BN partials (128 blocks = 1 per channel). No atomics anywhere.
__global__ void k_bnred(const float* __restrict__ part, float* __restrict__ stats) {
  int ch = blockIdx.x, tid = threadIdx.x;
  float s = part[(long)ch * 512 + tid] + part[(long)ch * 512 + 256 + tid];
  float q = part[65536 + (long)ch * 512 + tid] +
            part[65536 + (long)ch * 512 + 256 + tid];
  for (int off = 32; off; off >>= 1) {
    s += __shfl_down(s, off);
    q += __shfl_down(q, off);
  }
  __shared__ float rs[4], rq[4];
  if ((tid & 63) == 0) { rs[tid >> 6] = s; rq[tid >> 6] = q; }
  __syncthreads();
  if (tid == 0) {
    stats[ch] = rs[0] + rs[1] + rs[2] + rs[3];
    stats[128 + ch] = rq[0] + rq[1] + rq[2] + rq[3];
  }
}

// K12: BN + conv4 + sigmoid + gated residual — MFMA bf16 (BN folded in staging).
__global__ __launch_bounds__(256) void k_final(const unsigned short* __restrict__ o3,
                                               const float* __restrict__ stats,
                                               const float* __restrict__ bng,
                                               const float* __restrict__ bnb,
                                               const float* __restrict__ w,
                                               const float* __restrict__ bias,
                                               const float* __restrict__ x,
                                               float* __restrict__ out) {
  __shared__ unsigned short wT[64][140];
  __shared__ unsigned short aT[64][140];
  __shared__ float sc[128], sh[128];
  int b = blockIdx.y, l0 = blockIdx.x * 64, cb = blockIdx.z * 64;
  int tid = threadIdx.x, lane = tid & 63, mt = tid >> 6;
  int q = lane >> 4, i = lane & 15;
  if (tid < 128) {
    float mu = stats[tid] * (1.0f / 32768.0f);
    float var = stats[128 + tid] * (1.0f / 32768.0f) - mu * mu;
    float r = rsqrtf(var + 1e-5f);
    sc[tid] = r * bng[tid];
    sh[tid] = bnb[tid] - mu * r * bng[tid];
  }
  __syncthreads();
  int c4 = (tid & 15) * 4, k0 = (tid >> 4) * 2;
#pragma unroll
  for (int s = 0; s < 4; ++s) {
    int k = k0 + s * 32;
    float4 w0 = *(const float4*)&w[k * 128 + cb + c4];
    float4 w1 = *(const float4*)&w[(k + 1) * 128 + cb + c4];
    *(unsigned int*)&wT[c4 + 0][k] = pk2(w0.x, w1.x);
    *(unsigned int*)&wT[c4 + 1][k] = pk2(w0.y, w1.y);
    *(unsigned int*)&wT[c4 + 2][k] = pk2(w0.z, w1.z);
    *(unsigned int*)&wT[c4 + 3][k] = pk2(w0.w, w1.w);
    us4 a0 = *(const us4*)&o3[((long)b * 128 + k) * 4096 + l0 + c4];
    us4 a1 = *(const us4*)&o3[((long)b * 128 + k + 1) * 4096 + l0 + c4];
    float sc0 = sc[k], sh0 = sh[k], sc1 = sc[k + 1], sh1 = sh[k + 1];
#pragma unroll
    for (int j = 0; j < 4; ++j) {
      *(unsigned int*)&aT[c4 + j][k] =
          pk2(fmaf(frombf(a0[j]), sc0, sh0), fmaf(frombf(a1[j]), sc1, sh1));
    }
  }
  __syncthreads();
  short8 af[4];
#pragma unroll
  for (int kk = 0; kk < 4; ++kk)
    af[kk] = ldfrag(&wT[mt * 16 + i][q * 8 + 32 * kk]);
  float bv[4];
#pragma unroll
  for (int r2 = 0; r2 < 4; ++r2) bv[r2] = bias[cb + 16 * mt + q * 4 + r2];
#pragma unroll
  for (int nt = 0; nt < 4; ++nt) {
    f32x4 d = {0.f, 0.f, 0.f, 0.f};
#pragma unroll
    for (int kk = 0; kk < 4; ++kk) {
      short8 bfr = ldfrag(&aT[nt * 16 + i][q * 8 + 32 * kk]);
      d = __builtin_amdgcn_mfma_f32_16x16x32_bf16(af[kk], bfr, d, 0, 0, 0);
    }
#pragma unroll
    for (int r2 = 0; r2 < 4; ++r2) {
      int c = 16 * mt + q * 4 + r2;
      long xi = ((long)b * 128 + cb + c) * 4096 + l0 + nt * 16 + i;
      float g = 1.0f / (1.0f + expf(-(d[r2] + bv[r2])));
      out[xi] = x[xi] * (1.0f + g);
    }
  }
}

extern "C" void kernel_launch(void* const* d_in, const int* in_sizes, int n_in,
                              void* d_out, int out_size, void* d_ws, size_t ws_size,
                              hipStream_t stream) {
  const float* x          = (const float*)d_in[0];
  const float* lin1_w     = (const float*)d_in[1];
  const float* lin1_b     = (const float*)d_in[2];
  const float* dw_w       = (const float*)d_in[3];
  const float* dw_b       = (const float*)d_in[4];
  const float* fc_in_w    = (const float*)d_in[5];
  const float* mam_in_w   = (const float*)d_in[6];
  const float* mam_conv_w = (const float*)d_in[7];
  const float* mam_conv_b = (const float*)d_in[8];
  const float* mam_dt_bias= (const float*)d_in[9];
  const float* mam_A_log  = (const float*)d_in[10];
  const float* mam_D      = (const float*)d_in[11];
  const float* mam_norm_w = (const float*)d_in[12];
  const float* mam_out_w  = (const float*)d_in[13];
  const float* fc_out_w   = (const float*)d_in[14];
  const float* bn_g       = (const float*)d_in[15];
  const float* bn_b       = (const float*)d_in[16];
  const float* conv4_w    = (const float*)d_in[17];
  const float* conv4_b    = (const float*)d_in[18];
  float* out = (float*)d_out;
  float* ws  = (float*)d_ws;

  unsigned short* o1h  = (unsigned short*)(ws + OFF_O1);
  unsigned short* o2h  = (unsigned short*)(ws + OFF_O2);
  unsigned short* sbuf = (unsigned short*)(ws + OFF_S);
  unsigned short* zTb  = (unsigned short*)(ws + OFF_Z);
  unsigned short* WTb  = (unsigned short*)(ws + OFF_WT);
  unsigned short* xbca = (unsigned short*)(ws + OFF_XBCA);
  float* dts  = ws + OFF_DTS;
  float* cum  = ws + OFF_CUM;
  unsigned short* Tbufh = (unsigned short*)(ws + OFF_T);
  unsigned short* Sprev = (unsigned short*)(ws + OFF_SPREV);
  unsigned short* s2a = (unsigned short*)(ws + OFF_S2A);
  unsigned short* s2b = (unsigned short*)(ws + OFF_S2B);
  float* bnst = ws + OFF_BN;
  unsigned short* o3h = (unsigned short*)(ws + OFF_O3);
  float* part = ws + OFF_T;   // Tbuf dead after k_scan; reuse for BN partials

  k_lin1<<<dim3(64, 8, 2), 256, 0, stream>>>(x, lin1_w, lin1_b, o1h);
  k_dw<<<1024, 256, 0, stream>>>(o1h, dw_w, dw_b, o2h);
  k_fcin<<<dim3(64, 8), 256, 0, stream>>>(o2h, fc_in_w, sbuf, mam_in_w, WTb);
  k_inprojconv<<<dim3(64, 8, 2), 256, 0, stream>>>(sbuf, WTb, mam_conv_w, mam_conv_b,
                                                   mam_dt_bias, mam_A_log,
                                                   zTb, xbca, dts, cum, Tbufh);
  k_scan<<<256, 256, 0, stream>>>(Tbufh, cum, Sprev);
  k_chunkYout<<<dim3(512, 2), 256, 0, stream>>>(xbca, dts, cum, Sprev, mam_D, zTb,
                                                mam_norm_w, mam_out_w, s2a, s2b);
  k_fcout<<<dim3(64, 8, 2), 256, 0, stream>>>(s2a, s2b, fc_out_w, o3h, part);
  k_bnred<<<128, 256, 0, stream>>>(part, bnst);
  k_final<<<dim3(64, 8, 2), 256, 0, stream>>>(o3h, bnst, bn_g, bn_b, conv4_w, conv4_b, x, out);
}